// Round 6
// baseline (342.953 us; speedup 1.0000x reference)
//
#include <hip/hip_runtime.h>
#include <hip/hip_bf16.h>
#include <math.h>

#define L_SEQ 2048
#define DIM   2048
#define NH    16
#define HD    128
#define TDIM  6144

typedef __attribute__((ext_vector_type(8))) short short8;
typedef __attribute__((ext_vector_type(4))) float f32x4;
typedef __attribute__((ext_vector_type(4))) unsigned int u32x4;

// async global->LDS, 16 B per lane. LDS dest = wave-uniform base + lane*16.
__device__ __forceinline__ void gl_lds16(const void* g, void* l) {
  __builtin_amdgcn_global_load_lds(
      (const __attribute__((address_space(1))) unsigned int*)g,
      (__attribute__((address_space(3))) unsigned int*)l, 16, 0, 0);
}

__device__ __forceinline__ short bf16bits(float x) {
  __hip_bfloat16 h = __float2bfloat16(x);
  return *(short*)&h;
}

__device__ __forceinline__ float bits2f(short s) {
  unsigned int u = ((unsigned int)(unsigned short)s) << 16;
  return __uint_as_float(u);
}

// pack two f32 -> u32 of two bf16 (lo = a, hi = b)
__device__ __forceinline__ unsigned int pack_bf16(float a, float b) {
  __hip_bfloat162 h = __float22bfloat162_rn(make_float2(a, b));
  return *(unsigned int*)&h;
}

// ---------------------------------------------------------------------------
// fused fp32 -> bf16 cast of x (4M elems) then qkv_w (12M elems).
// ---------------------------------------------------------------------------
__global__ __launch_bounds__(256)
void cast2_bf16(const float* __restrict__ a, __hip_bfloat16* __restrict__ oa,
                const float* __restrict__ b, __hip_bfloat16* __restrict__ ob) {
  int i = (blockIdx.x * 256 + threadIdx.x) * 8;
  const float* src;
  __hip_bfloat16* dst;
  int off;
  if (i < DIM * DIM) { src = a; dst = oa; off = i; }
  else               { src = b; dst = ob; off = i - DIM * DIM; }
  float4 v0 = *(const float4*)(src + off);
  float4 v1 = *(const float4*)(src + off + 4);
  short8 o;
  o[0] = bf16bits(v0.x); o[1] = bf16bits(v0.y); o[2] = bf16bits(v0.z); o[3] = bf16bits(v0.w);
  o[4] = bf16bits(v1.x); o[5] = bf16bits(v1.y); o[6] = bf16bits(v1.z); o[7] = bf16bits(v1.w);
  *(short8*)(dst + off) = o;
}

__global__ __launch_bounds__(256)
void cast_bf16(const float* __restrict__ in, __hip_bfloat16* __restrict__ out, int n) {
  int i = (blockIdx.x * 256 + threadIdx.x) * 8;
  if (i >= n) return;
  float4 a = *(const float4*)(in + i);
  float4 b = *(const float4*)(in + i + 4);
  short8 o;
  o[0] = bf16bits(a.x); o[1] = bf16bits(a.y); o[2] = bf16bits(a.z); o[3] = bf16bits(a.w);
  o[4] = bf16bits(b.x); o[5] = bf16bits(b.y); o[6] = bf16bits(b.z); o[7] = bf16bits(b.w);
  *(short8*)(out + i) = o;
}

// ---------------------------------------------------------------------------
// bf16 MFMA GEMM (m97 structure) — unchanged, verified.
// ---------------------------------------------------------------------------
template<int OUT_MODE>
__global__ __launch_bounds__(256)
void gemm_mfma(const __hip_bfloat16* __restrict__ A, const __hip_bfloat16* __restrict__ B,
               const float* __restrict__ bias, void* __restrict__ Cout,
               int M, int N, int K) {
  const int n0 = blockIdx.x * 128, m0 = blockIdx.y * 128;
  const int t = threadIdx.x, lane = t & 63, w = t >> 6;
  const int l15 = lane & 15, quad = lane >> 4;
  const int wm = (w & 1) * 64, wn = (w >> 1) * 64;

  __shared__ __align__(16) __hip_bfloat16 As[128 * 32];
  __shared__ __align__(16) __hip_bfloat16 Bs[128 * 32];

  f32x4 acc[4][4];
#pragma unroll
  for (int mt = 0; mt < 4; ++mt)
#pragma unroll
    for (int nt = 0; nt < 4; ++nt) acc[mt][nt] = (f32x4){0.f, 0.f, 0.f, 0.f};

  const int arow  = lane >> 2;
  const int acol8 = (lane & 3) * 8;
  const __hip_bfloat16* Ab = A + (size_t)(m0 + w * 16 + arow) * K + acol8;
  const __hip_bfloat16* Bb = B + (size_t)(n0 + w * 16 + arow) * K + acol8;
  __hip_bfloat16* As_base = As + (size_t)(w * 16) * 32;
  __hip_bfloat16* Bs_base = Bs + (size_t)(w * 16) * 32;

  for (int kb = 0; kb < K; kb += 32) {
    gl_lds16(Ab + kb,                As_base);
    gl_lds16(Ab + kb + (size_t)64*K, As_base + 64 * 32);
    gl_lds16(Bb + kb,                Bs_base);
    gl_lds16(Bb + kb + (size_t)64*K, Bs_base + 64 * 32);
    __syncthreads();

    short8 am[4], bn[4];
#pragma unroll
    for (int mt = 0; mt < 4; ++mt)
      am[mt] = *(const short8*)&As[(size_t)(wm + mt*16 + l15) * 32 + quad * 8];
#pragma unroll
    for (int nt = 0; nt < 4; ++nt)
      bn[nt] = *(const short8*)&Bs[(size_t)(wn + nt*16 + l15) * 32 + quad * 8];
#pragma unroll
    for (int mt = 0; mt < 4; ++mt)
#pragma unroll
      for (int nt = 0; nt < 4; ++nt)
        acc[mt][nt] = __builtin_amdgcn_mfma_f32_16x16x32_bf16(am[mt], bn[nt], acc[mt][nt], 0, 0, 0);
    __syncthreads();
  }

#pragma unroll
  for (int mt = 0; mt < 4; ++mt) {
#pragma unroll
    for (int nt = 0; nt < 4; ++nt) {
      int col = n0 + wn + nt * 16 + l15;
#pragma unroll
      for (int r = 0; r < 4; ++r) {
        int row = m0 + wm + mt * 16 + quad * 4 + r;
        if (OUT_MODE == 0) {
          ((__hip_bfloat16*)Cout)[(size_t)row * N + col] = __float2bfloat16(acc[mt][nt][r]);
        } else {
          ((float*)Cout)[(size_t)row * N + col] = acc[mt][nt][r] + bias[col];
        }
      }
    }
  }
}

// ---------------------------------------------------------------------------
// RMSNorm + RoPE on q,k (unchanged — verified).
// ---------------------------------------------------------------------------
__global__ __launch_bounds__(128)
void norm_rope(const __hip_bfloat16* __restrict__ qkv_b, const float* __restrict__ pe,
               const float* __restrict__ q_scale, const float* __restrict__ k_scale,
               __hip_bfloat16* __restrict__ Qb, __hip_bfloat16* __restrict__ Kb) {
  const int l  = blockIdx.x;
  const int hh = blockIdx.y;
  const int qk_sel = hh >> 4;
  const int h  = hh & 15;
  const int d  = threadIdx.x;
  const __hip_bfloat16* row = qkv_b + (size_t)l * TDIM + qk_sel * DIM + h * HD;
  const float* scale = qk_sel ? k_scale : q_scale;

  float v  = __bfloat162float(row[d]);
  float sq = v * v;
#pragma unroll
  for (int o = 32; o > 0; o >>= 1) sq += __shfl_xor(sq, o);
  __shared__ float wsum[2];
  if ((d & 63) == 0) wsum[d >> 6] = sq;
  __syncthreads();
  float rrms = rsqrtf((wsum[0] + wsum[1]) * (1.f / 128.f) + 1e-6f);
  __shared__ float nb[128];
  nb[d] = v * rrms * scale[d];
  __syncthreads();
  int i = d >> 1, c = d & 1;
  const float* p = pe + ((size_t)(l * 64 + i) * 2 + c) * 2;
  float res = p[0] * nb[2*i] + p[1] * nb[2*i + 1];
  size_t o_idx = ((size_t)h * L_SEQ + l) * HD + d;
  if (qk_sel == 0) Qb[o_idx] = __float2bfloat16(res * 0.08838834764831845f);
  else             Kb[o_idx] = __float2bfloat16(res);
}

// ---------------------------------------------------------------------------
// Transpose V -> Vt[h][d][l] bf16 (unchanged — verified).
// ---------------------------------------------------------------------------
__global__ __launch_bounds__(256)
void v_transpose(const __hip_bfloat16* __restrict__ qkv_b, __hip_bfloat16* __restrict__ Vt) {
  const int l0 = blockIdx.x * 64;
  const int h  = blockIdx.y;
  const int t  = threadIdx.x;
  __shared__ __align__(16) __hip_bfloat16 T[128][72];
#pragma unroll
  for (int it = 0; it < 4; ++it) {
    int idx = t + it * 256;
    int row = idx >> 4;
    int c8  = (idx & 15) * 8;
    short8 v = *(const short8*)&qkv_b[(size_t)(l0 + row) * TDIM + 2 * DIM + h * HD + c8];
#pragma unroll
    for (int j = 0; j < 8; ++j) *(short*)&T[c8 + j][row] = v[j];
  }
  __syncthreads();
#pragma unroll
  for (int it = 0; it < 4; ++it) {
    int idx = t + it * 256;
    int d = idx >> 3, c8 = (idx & 7) * 8;
    *(short8*)(Vt + ((size_t)h * HD + d) * L_SEQ + l0 + c8) = *(const short8*)&T[d][c8];
  }
}

// ---------------------------------------------------------------------------
// Flash attention v4: KV-split (grid.z=2, 1024 kv each), 4 blocks/CU.
// S^T formulation + in-register softmax/transpose (verified R5 inner loop).
// Single-buffered K/V (LDS 32 KB), stage->barrier->compute->barrier per tile.
// Writes normalized partial O (bf16) + (m,l) per q; combined by attn_combine.
// ---------------------------------------------------------------------------
__global__ __launch_bounds__(256, 4)
void attn_mfma(const __hip_bfloat16* __restrict__ Qb,
               const __hip_bfloat16* __restrict__ Kb,
               const __hip_bfloat16* __restrict__ Vt,
               __hip_bfloat16* __restrict__ Opart, float2* __restrict__ ml) {
  const int q0 = blockIdx.x * 64;
  const int h  = blockIdx.y;
  const int z  = blockIdx.z;
  const int t  = threadIdx.x;
  const int lane = t & 63, w = t >> 6;
  const int l15 = lane & 15, quad = lane >> 4;
  const int sw = l15 & 7;                    // read-side XOR swizzle key

  __shared__ __align__(16) __hip_bfloat16 Ks[64 * 128];   // [row][chunk ^ (row&7)]
  __shared__ __align__(16) __hip_bfloat16 Vs[128 * 64];   // [d][chunk ^ (d&7)]

  const __hip_bfloat16* kbase = Kb + (size_t)h * L_SEQ * HD;
  const __hip_bfloat16* vbase = Vt + (size_t)h * HD * L_SEQ;

  // Q fragments (B-operand): q = w*16 + l15, k = ks*32 + quad*8
  short8 aq[4];
  {
    const __hip_bfloat16* qbase = Qb + ((size_t)h * L_SEQ + q0 + w * 16 + l15) * HD;
#pragma unroll
    for (int ks = 0; ks < 4; ++ks)
      aq[ks] = *(const short8*)(qbase + ks * 32 + quad * 8);
  }

  f32x4 o[8];
#pragma unroll
  for (int n2 = 0; n2 < 8; ++n2) o[n2] = (f32x4){0.f, 0.f, 0.f, 0.f};
  float m_run = -1e30f, l_run = 0.f;   // per lane, q = w*16 + l15 (dup x4 quads)

  for (int kt = 0; kt < 16; ++kt) {
    const int k0 = z * (L_SEQ / 2) + kt * 64;
    // ---- stage K (64x128) and Vt (128x64), XOR-swizzled, async ----
#pragma unroll
    for (int i = 0; i < 4; ++i) {
      int krow = w * 16 + i * 4 + (lane >> 4);
      int kch  = (lane & 15) ^ (krow & 7);
      gl_lds16(kbase + (size_t)(k0 + krow) * HD + kch * 8,
               &Ks[(w * 16 + i * 4) * 128]);
    }
#pragma unroll
    for (int i = 0; i < 4; ++i) {
      int vrow = w * 32 + i * 8 + (lane >> 3);
      int vch  = (lane & 7) ^ (vrow & 7);
      gl_lds16(vbase + (size_t)vrow * L_SEQ + k0 + vch * 8,
               &Vs[(w * 32 + i * 8) * 64]);
    }
    __syncthreads();   // vmcnt drained: staged data visible

    // ---- S^T = K Q^T : 16 MFMA. s[nt][r]: kv = nt*16+quad*4+r, q = l15 ----
    f32x4 s[4];
#pragma unroll
    for (int nt = 0; nt < 4; ++nt) s[nt] = (f32x4){0.f, 0.f, 0.f, 0.f};
#pragma unroll
    for (int ks = 0; ks < 4; ++ks) {
      short8 bk[4];
#pragma unroll
      for (int nt = 0; nt < 4; ++nt)
        bk[nt] = *(const short8*)&Ks[(nt * 16 + l15) * 128 + ((ks * 4 + quad) ^ sw) * 8];
#pragma unroll
      for (int nt = 0; nt < 4; ++nt)
        s[nt] = __builtin_amdgcn_mfma_f32_16x16x32_bf16(bk[nt], aq[ks], s[nt], 0, 0, 0);
    }

    // ---- online softmax, in-register + cross-quad ----
    float mx0 = fmaxf(fmaxf(s[0][0], s[0][1]), fmaxf(s[0][2], s[0][3]));
    float mx1 = fmaxf(fmaxf(s[1][0], s[1][1]), fmaxf(s[1][2], s[1][3]));
    float mx2 = fmaxf(fmaxf(s[2][0], s[2][1]), fmaxf(s[2][2], s[2][3]));
    float mx3 = fmaxf(fmaxf(s[3][0], s[3][1]), fmaxf(s[3][2], s[3][3]));
    float rm = fmaxf(fmaxf(mx0, mx1), fmaxf(mx2, mx3));
    rm = fmaxf(rm, __shfl_xor(rm, 16));
    rm = fmaxf(rm, __shfl_xor(rm, 32));
    float mnew = fmaxf(m_run, rm);
    float alpha = __expf(m_run - mnew);
    m_run = mnew;

    float sum = 0.f;
#pragma unroll
    for (int nt = 0; nt < 4; ++nt)
#pragma unroll
      for (int r = 0; r < 4; ++r) {
        float p = __expf(s[nt][r] - mnew);
        s[nt][r] = p;
        sum += p;
      }
    sum += __shfl_xor(sum, 16);
    sum += __shfl_xor(sum, 32);
    l_run = l_run * alpha + sum;

    // O *= alpha (alpha for q=quad*4+r lives at lane quad*4+r)
    float alpha_r[4];
#pragma unroll
    for (int r = 0; r < 4; ++r) alpha_r[r] = __shfl(alpha, quad * 4 + r);
#pragma unroll
    for (int n2 = 0; n2 < 8; ++n2)
#pragma unroll
      for (int r = 0; r < 4; ++r) o[n2][r] *= alpha_r[r];

    // ---- P: C-layout -> A-layout in-register (16 shfl + 8 sel) ----
    unsigned int pk[4][2];
#pragma unroll
    for (int nt = 0; nt < 4; ++nt) {
      pk[nt][0] = pack_bf16(s[nt][0], s[nt][1]);
      pk[nt][1] = pack_bf16(s[nt][2], s[nt][3]);
    }
    short8 ap[2];
#pragma unroll
    for (int ks2 = 0; ks2 < 2; ++ks2) {
      u32x4 a32;
#pragma unroll
      for (int jp = 0; jp < 4; ++jp) {
        int quad_src = (quad & 1) * 2 + (jp >> 1);
        int src = (quad_src << 4) | l15;
        int rp = jp & 1;
        unsigned int v0 = __shfl((int)pk[2 * ks2 + 0][rp], src);
        unsigned int v1 = __shfl((int)pk[2 * ks2 + 1][rp], src);
        a32[jp] = (quad >> 1) ? v1 : v0;
      }
      ap[ks2] = *(short8*)&a32;
    }

    // ---- O += P Vt^T : 16 MFMA ----
#pragma unroll
    for (int ks2 = 0; ks2 < 2; ++ks2)
#pragma unroll
      for (int n2 = 0; n2 < 8; ++n2) {
        short8 bv = *(const short8*)&Vs[(n2 * 16 + l15) * 64 + ((ks2 * 4 + quad) ^ sw) * 8];
        o[n2] = __builtin_amdgcn_mfma_f32_16x16x32_bf16(ap[ks2], bv, o[n2], 0, 0, 0);
      }

    __syncthreads();   // all waves done with Ks/Vs before next stage
  }

  // epilogue: normalized partial O (bf16) + (m,l) fp32
  const size_t rb = (size_t)(z * NH + h) * L_SEQ + q0 + w * 16;
  float linv[4];
#pragma unroll
  for (int r = 0; r < 4; ++r) linv[r] = 1.f / __shfl(l_run, quad * 4 + r);
#pragma unroll
  for (int r = 0; r < 4; ++r) {
    size_t row = rb + quad * 4 + r;
#pragma unroll
    for (int n2 = 0; n2 < 8; ++n2)
      Opart[row * HD + n2 * 16 + l15] = __float2bfloat16(o[n2][r] * linv[r]);
  }
  if (quad == 0) ml[rb + l15] = make_float2(m_run, l_run);
}

// ---------------------------------------------------------------------------
// Combine the two KV-split halves:
// O = (w1*l1*O1 + w2*l2*O2) / (w1*l1 + w2*l2), w_i = exp(m_i - max).
// Writes attn_out[q][h*128+d] bf16. Block: 256 thr = 16 q x 16 d-chunks.
// ---------------------------------------------------------------------------
__global__ __launch_bounds__(256)
void attn_combine(const __hip_bfloat16* __restrict__ Opart,
                  const float2* __restrict__ ml,
                  __hip_bfloat16* __restrict__ out) {
  const int h  = blockIdx.y;
  const int q  = blockIdx.x * 16 + (threadIdx.x >> 4);
  const int d8 = (threadIdx.x & 15) * 8;
  const size_t i0 = (size_t)h * L_SEQ + q;
  const size_t i1 = (size_t)(NH + h) * L_SEQ + q;
  float2 a = ml[i0], b = ml[i1];
  float M  = fmaxf(a.x, b.x);
  float w1 = __expf(a.x - M) * a.y;
  float w2 = __expf(b.x - M) * b.y;
  float inv = 1.f / (w1 + w2);
  w1 *= inv; w2 *= inv;
  short8 o1 = *(const short8*)&Opart[i0 * HD + d8];
  short8 o2 = *(const short8*)&Opart[i1 * HD + d8];
  short8 r;
#pragma unroll
  for (int j = 0; j < 8; ++j)
    r[j] = bf16bits(w1 * bits2f(o1[j]) + w2 * bits2f(o2[j]));
  *(short8*)&out[(size_t)q * DIM + h * HD + d8] = r;
}

// ---------------------------------------------------------------------------
extern "C" void kernel_launch(void* const* d_in, const int* in_sizes, int n_in,
                              void* d_out, int out_size, void* d_ws, size_t ws_size,
                              hipStream_t stream) {
  const float* x       = (const float*)d_in[0];
  const float* pe      = (const float*)d_in[1];
  const float* qkv_w   = (const float*)d_in[2];
  const float* q_scale = (const float*)d_in[3];
  const float* k_scale = (const float*)d_in[4];
  const float* proj_w  = (const float*)d_in[5];
  const float* proj_b  = (const float*)d_in[6];
  float* out = (float*)d_out;

  // Workspace aliasing (67.1 MB proven footprint):
  //  [0, 25165824):        wb (qkv_w bf16) -> Qb@0 | Kb@8.4M | Vt@16.8M -> attn_out@0
  //  [25165824, 50331648): qkv_b bf16 -> pwb@25.2M (8.4M) + Opart@33.6M (16.8M)
  //  [50331648, 58720256): xb (x bf16) -> ml@50.3M (0.5M)
  char* base = (char*)d_ws;
  __hip_bfloat16* wb       = (__hip_bfloat16*)base;
  __hip_bfloat16* qkv_b    = (__hip_bfloat16*)(base + 25165824);
  __hip_bfloat16* xb       = (__hip_bfloat16*)(base + 50331648);
  __hip_bfloat16* Qb       = (__hip_bfloat16*)base;
  __hip_bfloat16* Kb       = (__hip_bfloat16*)(base + 8388608);
  __hip_bfloat16* Vt       = (__hip_bfloat16*)(base + 16777216);
  __hip_bfloat16* pwb      = (__hip_bfloat16*)(base + 25165824);
  __hip_bfloat16* Opart    = (__hip_bfloat16*)(base + 33554432);
  float2*         ml       = (float2*)(base + 50331648);
  __hip_bfloat16* attn_out = (__hip_bfloat16*)base;   // aliases dead Qb

  cast2_bf16<<<dim3((DIM * DIM + TDIM * DIM) / (256 * 8)), 256, 0, stream>>>(
      x, xb, qkv_w, wb);

  gemm_mfma<0><<<dim3(TDIM / 128, L_SEQ / 128), 256, 0, stream>>>(
      xb, wb, nullptr, qkv_b, L_SEQ, TDIM, DIM);

  norm_rope<<<dim3(L_SEQ, 2 * NH), 128, 0, stream>>>(qkv_b, pe, q_scale, k_scale, Qb, Kb);
  v_transpose<<<dim3(L_SEQ / 64, NH), 256, 0, stream>>>(qkv_b, Vt);

  cast_bf16<<<dim3(DIM * DIM / (256 * 8)), 256, 0, stream>>>(proj_w, pwb, DIM * DIM);

  attn_mfma<<<dim3(L_SEQ / 64, NH, 2), 256, 0, stream>>>(Qb, Kb, Vt, Opart, ml);
  attn_combine<<<dim3(L_SEQ / 16, NH), 256, 0, stream>>>(Opart, ml, attn_out);

  gemm_mfma<1><<<dim3(DIM / 128, DIM / 128), 256, 0, stream>>>(
      attn_out, pwb, proj_b, out, L_SEQ, DIM, DIM);
}

// Round 8
// 340.737 us; speedup vs baseline: 1.0065x; 1.0065x over previous
//
#include <hip/hip_runtime.h>
#include <hip/hip_bf16.h>
#include <math.h>

#define L_SEQ 2048
#define DIM   2048
#define NH    16
#define HD    128
#define TDIM  6144

typedef __attribute__((ext_vector_type(8))) short short8;
typedef __attribute__((ext_vector_type(4))) float f32x4;
typedef __attribute__((ext_vector_type(4))) unsigned int u32x4;

// async global->LDS, 16 B per lane. LDS dest = wave-uniform base + lane*16.
__device__ __forceinline__ void gl_lds16(const void* g, void* l) {
  __builtin_amdgcn_global_load_lds(
      (const __attribute__((address_space(1))) unsigned int*)g,
      (__attribute__((address_space(3))) unsigned int*)l, 16, 0, 0);
}

__device__ __forceinline__ short bf16bits(float x) {
  __hip_bfloat16 h = __float2bfloat16(x);
  return *(short*)&h;
}

__device__ __forceinline__ float bits2f(short s) {
  unsigned int u = ((unsigned int)(unsigned short)s) << 16;
  return __uint_as_float(u);
}

__device__ __forceinline__ unsigned int pack_bf16(float a, float b) {
  __hip_bfloat162 h = __float22bfloat162_rn(make_float2(a, b));
  return *(unsigned int*)&h;
}

// ---------------------------------------------------------------------------
// fused fp32 -> bf16 cast of x (4M elems) then qkv_w (12M elems).
// ---------------------------------------------------------------------------
__global__ __launch_bounds__(256)
void cast2_bf16(const float* __restrict__ a, __hip_bfloat16* __restrict__ oa,
                const float* __restrict__ b, __hip_bfloat16* __restrict__ ob) {
  int i = (blockIdx.x * 256 + threadIdx.x) * 8;
  const float* src;
  __hip_bfloat16* dst;
  int off;
  if (i < DIM * DIM) { src = a; dst = oa; off = i; }
  else               { src = b; dst = ob; off = i - DIM * DIM; }
  float4 v0 = *(const float4*)(src + off);
  float4 v1 = *(const float4*)(src + off + 4);
  short8 o;
  o[0] = bf16bits(v0.x); o[1] = bf16bits(v0.y); o[2] = bf16bits(v0.z); o[3] = bf16bits(v0.w);
  o[4] = bf16bits(v1.x); o[5] = bf16bits(v1.y); o[6] = bf16bits(v1.z); o[7] = bf16bits(v1.w);
  *(short8*)(dst + off) = o;
}

__global__ __launch_bounds__(256)
void cast_bf16(const float* __restrict__ in, __hip_bfloat16* __restrict__ out, int n) {
  int i = (blockIdx.x * 256 + threadIdx.x) * 8;
  if (i >= n) return;
  float4 a = *(const float4*)(in + i);
  float4 b = *(const float4*)(in + i + 4);
  short8 o;
  o[0] = bf16bits(a.x); o[1] = bf16bits(a.y); o[2] = bf16bits(a.z); o[3] = bf16bits(a.w);
  o[4] = bf16bits(b.x); o[5] = bf16bits(b.y); o[6] = bf16bits(b.z); o[7] = bf16bits(b.w);
  *(short8*)(out + i) = o;
}

// ---------------------------------------------------------------------------
// QKV GEMM with fused epilogue, v2.
// R7's in-register shfl epilogue FAILED (absmax 0.49, bug not found by
// inspection) — this version routes the C-tile through LDS (bf16 T[l][d],
// same dataflow as the verified R6 norm_rope: bf16 values feed ss) and does
// RoPE thread-locally (pairs never cross the 64-wide half a thread owns).
// Col-tile bx: [0,16) q-head -> RMSNorm+RoPE+1/sqrt(HD) -> Qb[h][l][d]
//              [16,32) k-head -> RMSNorm+RoPE            -> Kb[h][l][d]
//              [32,48) v-head -> LDS transpose           -> Vt[h][d][l]
// ---------------------------------------------------------------------------
__global__ __launch_bounds__(256)
void gemm_qkv_fused(const __hip_bfloat16* __restrict__ A, const __hip_bfloat16* __restrict__ B,
                    const float* __restrict__ q_scale, const float* __restrict__ k_scale,
                    const float* __restrict__ pe,
                    __hip_bfloat16* __restrict__ Qb, __hip_bfloat16* __restrict__ Kb,
                    __hip_bfloat16* __restrict__ Vt) {
  const int K = DIM;
  const int bx = blockIdx.x;
  const int n0 = bx * 128, m0 = blockIdx.y * 128;
  const int t = threadIdx.x, lane = t & 63, w = t >> 6;
  const int l15 = lane & 15, quad = lane >> 4;
  const int wm = (w & 1) * 64, wn = (w >> 1) * 64;

  // LDS: As/Bs (8 KB each) during K-loop; T[128][136] bf16 (34.8 KB) reuses
  // the same space in the epilogue (after the K-loop's final barrier).
  __shared__ __align__(16) char smem[128 * 136 * 2];
  __hip_bfloat16* As = (__hip_bfloat16*)smem;
  __hip_bfloat16* Bs = As + 128 * 32;

  f32x4 acc[4][4];
#pragma unroll
  for (int mt = 0; mt < 4; ++mt)
#pragma unroll
    for (int nt = 0; nt < 4; ++nt) acc[mt][nt] = (f32x4){0.f, 0.f, 0.f, 0.f};

  const int arow  = lane >> 2;
  const int acol8 = (lane & 3) * 8;
  const __hip_bfloat16* Ab = A + (size_t)(m0 + w * 16 + arow) * K + acol8;
  const __hip_bfloat16* Bb = B + (size_t)(n0 + w * 16 + arow) * K + acol8;
  __hip_bfloat16* As_base = As + (size_t)(w * 16) * 32;
  __hip_bfloat16* Bs_base = Bs + (size_t)(w * 16) * 32;

  for (int kb = 0; kb < K; kb += 32) {
    gl_lds16(Ab + kb,                As_base);
    gl_lds16(Ab + kb + (size_t)64*K, As_base + 64 * 32);
    gl_lds16(Bb + kb,                Bs_base);
    gl_lds16(Bb + kb + (size_t)64*K, Bs_base + 64 * 32);
    __syncthreads();

    short8 am[4], bn[4];
#pragma unroll
    for (int mt = 0; mt < 4; ++mt)
      am[mt] = *(const short8*)&As[(size_t)(wm + mt*16 + l15) * 32 + quad * 8];
#pragma unroll
    for (int nt = 0; nt < 4; ++nt)
      bn[nt] = *(const short8*)&Bs[(size_t)(wn + nt*16 + l15) * 32 + quad * 8];
#pragma unroll
    for (int mt = 0; mt < 4; ++mt)
#pragma unroll
      for (int nt = 0; nt < 4; ++nt)
        acc[mt][nt] = __builtin_amdgcn_mfma_f32_16x16x32_bf16(am[mt], bn[nt], acc[mt][nt], 0, 0, 0);
    __syncthreads();
  }

  __hip_bfloat16* T = (__hip_bfloat16*)smem;   // [128][136]

  if (bx < 32) {
    // ---- q/k head: RMSNorm + RoPE via LDS round-trip ----
    const float* scale = (bx < 16) ? q_scale : k_scale;
    const float qmul = (bx < 16) ? 0.08838834764831845f : 1.0f;
    __hip_bfloat16* dst = (bx < 16) ? Qb : Kb;
    const int h = bx & 15;

    // C-tile -> LDS bf16, row-major T[l_local][d]
#pragma unroll
    for (int mt = 0; mt < 4; ++mt)
#pragma unroll
      for (int nt = 0; nt < 4; ++nt) {
        int d = wn + nt * 16 + l15;
#pragma unroll
        for (int r = 0; r < 4; ++r)
          T[(wm + mt * 16 + quad * 4 + r) * 136 + d] = __float2bfloat16(acc[mt][nt][r]);
      }
    __syncthreads();

    // thread t owns (row = t>>1, d-half = t&1): 64 contiguous d values.
    const int row  = t >> 1;
    const int half = t & 1;
    const __hip_bfloat16* Trow = T + row * 136 + half * 64;

    float ss = 0.f;
#pragma unroll
    for (int c8 = 0; c8 < 64; c8 += 8) {
      short8 v8 = *(const short8*)(Trow + c8);
#pragma unroll
      for (int j = 0; j < 8; ++j) { float f = bits2f(v8[j]); ss += f * f; }
    }
    ss += __shfl_xor(ss, 1);   // partner thread = other half, same row
    const float rrms = rsqrtf(ss * (1.f / 128.f) + 1e-6f);

    const int l = m0 + row;
    const float* perow = pe + (size_t)l * 256 + half * 128;   // 64 d = 32 pairs = 128 floats
    __hip_bfloat16* drow = dst + ((size_t)h * L_SEQ + l) * HD + half * 64;

#pragma unroll
    for (int c8 = 0; c8 < 64; c8 += 8) {
      short8 v8 = *(const short8*)(Trow + c8);
      float f[8];
#pragma unroll
      for (int j = 0; j < 8; ++j)
        f[j] = bits2f(v8[j]) * rrms * scale[half * 64 + c8 + j];
      short8 o;
#pragma unroll
      for (int p = 0; p < 4; ++p) {
        // pair (d_even, d_odd) = (half*64 + c8 + 2p, +1); i = d_even/2
        float4 pp = *(const float4*)(perow + c8 * 2 + p * 4);  // pe[l][i][0][0..1], pe[l][i][1][0..1]
        float e = f[2 * p], od = f[2 * p + 1];
        o[2 * p]     = bf16bits((pp.x * e + pp.y * od) * qmul);
        o[2 * p + 1] = bf16bits((pp.z * e + pp.w * od) * qmul);
      }
      *(short8*)(drow + c8) = o;
    }
  } else {
    // ---- v head: LDS transpose -> Vt[h][d][l] (verified R7-identical) ----
    const int h = bx - 32;
#pragma unroll
    for (int mt = 0; mt < 4; ++mt)
#pragma unroll
      for (int nt = 0; nt < 4; ++nt) {
        int d = wn + nt * 16 + l15;
#pragma unroll
        for (int r = 0; r < 4; ++r) {
          int l_local = wm + mt * 16 + quad * 4 + r;
          T[d * 136 + l_local] = __float2bfloat16(acc[mt][nt][r]);
        }
      }
    __syncthreads();
#pragma unroll
    for (int it = 0; it < 8; ++it) {
      int idx = t + it * 256;
      int d = idx >> 4, c8 = (idx & 15) * 8;
      short8 v = *(const short8*)&T[d * 136 + c8];
      *(short8*)&Vt[((size_t)h * HD + d) * L_SEQ + m0 + c8] = v;
    }
  }
}

// ---------------------------------------------------------------------------
// bf16 MFMA GEMM (m97 structure) — proj only (fp32 out + bias). Verified.
// ---------------------------------------------------------------------------
__global__ __launch_bounds__(256)
void gemm_proj(const __hip_bfloat16* __restrict__ A, const __hip_bfloat16* __restrict__ B,
               const float* __restrict__ bias, float* __restrict__ C,
               int M, int N, int K) {
  const int n0 = blockIdx.x * 128, m0 = blockIdx.y * 128;
  const int t = threadIdx.x, lane = t & 63, w = t >> 6;
  const int l15 = lane & 15, quad = lane >> 4;
  const int wm = (w & 1) * 64, wn = (w >> 1) * 64;

  __shared__ __align__(16) __hip_bfloat16 As[128 * 32];
  __shared__ __align__(16) __hip_bfloat16 Bs[128 * 32];

  f32x4 acc[4][4];
#pragma unroll
  for (int mt = 0; mt < 4; ++mt)
#pragma unroll
    for (int nt = 0; nt < 4; ++nt) acc[mt][nt] = (f32x4){0.f, 0.f, 0.f, 0.f};

  const int arow  = lane >> 2;
  const int acol8 = (lane & 3) * 8;
  const __hip_bfloat16* Ab = A + (size_t)(m0 + w * 16 + arow) * K + acol8;
  const __hip_bfloat16* Bb = B + (size_t)(n0 + w * 16 + arow) * K + acol8;
  __hip_bfloat16* As_base = As + (size_t)(w * 16) * 32;
  __hip_bfloat16* Bs_base = Bs + (size_t)(w * 16) * 32;

  for (int kb = 0; kb < K; kb += 32) {
    gl_lds16(Ab + kb,                As_base);
    gl_lds16(Ab + kb + (size_t)64*K, As_base + 64 * 32);
    gl_lds16(Bb + kb,                Bs_base);
    gl_lds16(Bb + kb + (size_t)64*K, Bs_base + 64 * 32);
    __syncthreads();

    short8 am[4], bn[4];
#pragma unroll
    for (int mt = 0; mt < 4; ++mt)
      am[mt] = *(const short8*)&As[(size_t)(wm + mt*16 + l15) * 32 + quad * 8];
#pragma unroll
    for (int nt = 0; nt < 4; ++nt)
      bn[nt] = *(const short8*)&Bs[(size_t)(wn + nt*16 + l15) * 32 + quad * 8];
#pragma unroll
    for (int mt = 0; mt < 4; ++mt)
#pragma unroll
      for (int nt = 0; nt < 4; ++nt)
        acc[mt][nt] = __builtin_amdgcn_mfma_f32_16x16x32_bf16(am[mt], bn[nt], acc[mt][nt], 0, 0, 0);
    __syncthreads();
  }

#pragma unroll
  for (int mt = 0; mt < 4; ++mt)
#pragma unroll
    for (int nt = 0; nt < 4; ++nt) {
      int col = n0 + wn + nt * 16 + l15;
#pragma unroll
      for (int r = 0; r < 4; ++r) {
        int row = m0 + wm + mt * 16 + quad * 4 + r;
        C[(size_t)row * N + col] = acc[mt][nt][r] + bias[col];
      }
    }
}

// ---------------------------------------------------------------------------
// Flash attention: KV-split (grid.z=2), S^T formulation — verified R6.
// ---------------------------------------------------------------------------
__global__ __launch_bounds__(256, 4)
void attn_mfma(const __hip_bfloat16* __restrict__ Qb,
               const __hip_bfloat16* __restrict__ Kb,
               const __hip_bfloat16* __restrict__ Vt,
               __hip_bfloat16* __restrict__ Opart, float2* __restrict__ ml) {
  const int q0 = blockIdx.x * 64;
  const int h  = blockIdx.y;
  const int z  = blockIdx.z;
  const int t  = threadIdx.x;
  const int lane = t & 63, w = t >> 6;
  const int l15 = lane & 15, quad = lane >> 4;
  const int sw = l15 & 7;

  __shared__ __align__(16) __hip_bfloat16 Ks[64 * 128];
  __shared__ __align__(16) __hip_bfloat16 Vs[128 * 64];

  const __hip_bfloat16* kbase = Kb + (size_t)h * L_SEQ * HD;
  const __hip_bfloat16* vbase = Vt + (size_t)h * HD * L_SEQ;

  short8 aq[4];
  {
    const __hip_bfloat16* qbase = Qb + ((size_t)h * L_SEQ + q0 + w * 16 + l15) * HD;
#pragma unroll
    for (int ks = 0; ks < 4; ++ks)
      aq[ks] = *(const short8*)(qbase + ks * 32 + quad * 8);
  }

  f32x4 o[8];
#pragma unroll
  for (int n2 = 0; n2 < 8; ++n2) o[n2] = (f32x4){0.f, 0.f, 0.f, 0.f};
  float m_run = -1e30f, l_run = 0.f;

  for (int kt = 0; kt < 16; ++kt) {
    const int k0 = z * (L_SEQ / 2) + kt * 64;
#pragma unroll
    for (int i = 0; i < 4; ++i) {
      int krow = w * 16 + i * 4 + (lane >> 4);
      int kch  = (lane & 15) ^ (krow & 7);
      gl_lds16(kbase + (size_t)(k0 + krow) * HD + kch * 8,
               &Ks[(w * 16 + i * 4) * 128]);
    }
#pragma unroll
    for (int i = 0; i < 4; ++i) {
      int vrow = w * 32 + i * 8 + (lane >> 3);
      int vch  = (lane & 7) ^ (vrow & 7);
      gl_lds16(vbase + (size_t)vrow * L_SEQ + k0 + vch * 8,
               &Vs[(w * 32 + i * 8) * 64]);
    }
    __syncthreads();

    f32x4 s[4];
#pragma unroll
    for (int nt = 0; nt < 4; ++nt) s[nt] = (f32x4){0.f, 0.f, 0.f, 0.f};
#pragma unroll
    for (int ks = 0; ks < 4; ++ks) {
      short8 bk[4];
#pragma unroll
      for (int nt = 0; nt < 4; ++nt)
        bk[nt] = *(const short8*)&Ks[(nt * 16 + l15) * 128 + ((ks * 4 + quad) ^ sw) * 8];
#pragma unroll
      for (int nt = 0; nt < 4; ++nt)
        s[nt] = __builtin_amdgcn_mfma_f32_16x16x32_bf16(bk[nt], aq[ks], s[nt], 0, 0, 0);
    }

    float mx0 = fmaxf(fmaxf(s[0][0], s[0][1]), fmaxf(s[0][2], s[0][3]));
    float mx1 = fmaxf(fmaxf(s[1][0], s[1][1]), fmaxf(s[1][2], s[1][3]));
    float mx2 = fmaxf(fmaxf(s[2][0], s[2][1]), fmaxf(s[2][2], s[2][3]));
    float mx3 = fmaxf(fmaxf(s[3][0], s[3][1]), fmaxf(s[3][2], s[3][3]));
    float rm = fmaxf(fmaxf(mx0, mx1), fmaxf(mx2, mx3));
    rm = fmaxf(rm, __shfl_xor(rm, 16));
    rm = fmaxf(rm, __shfl_xor(rm, 32));
    float mnew = fmaxf(m_run, rm);
    float alpha = __expf(m_run - mnew);
    m_run = mnew;

    float sum = 0.f;
#pragma unroll
    for (int nt = 0; nt < 4; ++nt)
#pragma unroll
      for (int r = 0; r < 4; ++r) {
        float p = __expf(s[nt][r] - mnew);
        s[nt][r] = p;
        sum += p;
      }
    sum += __shfl_xor(sum, 16);
    sum += __shfl_xor(sum, 32);
    l_run = l_run * alpha + sum;

    float alpha_r[4];
#pragma unroll
    for (int r = 0; r < 4; ++r) alpha_r[r] = __shfl(alpha, quad * 4 + r);
#pragma unroll
    for (int n2 = 0; n2 < 8; ++n2)
#pragma unroll
      for (int r = 0; r < 4; ++r) o[n2][r] *= alpha_r[r];

    unsigned int pk[4][2];
#pragma unroll
    for (int nt = 0; nt < 4; ++nt) {
      pk[nt][0] = pack_bf16(s[nt][0], s[nt][1]);
      pk[nt][1] = pack_bf16(s[nt][2], s[nt][3]);
    }
    short8 ap[2];
#pragma unroll
    for (int ks2 = 0; ks2 < 2; ++ks2) {
      u32x4 a32;
#pragma unroll
      for (int jp = 0; jp < 4; ++jp) {
        int quad_src = (quad & 1) * 2 + (jp >> 1);
        int src = (quad_src << 4) | l15;
        int rp = jp & 1;
        unsigned int v0 = __shfl((int)pk[2 * ks2 + 0][rp], src);
        unsigned int v1 = __shfl((int)pk[2 * ks2 + 1][rp], src);
        a32[jp] = (quad >> 1) ? v1 : v0;
      }
      ap[ks2] = *(short8*)&a32;
    }

#pragma unroll
    for (int ks2 = 0; ks2 < 2; ++ks2)
#pragma unroll
      for (int n2 = 0; n2 < 8; ++n2) {
        short8 bv = *(const short8*)&Vs[(n2 * 16 + l15) * 64 + ((ks2 * 4 + quad) ^ sw) * 8];
        o[n2] = __builtin_amdgcn_mfma_f32_16x16x32_bf16(ap[ks2], bv, o[n2], 0, 0, 0);
      }

    __syncthreads();
  }

  const size_t rb = (size_t)(z * NH + h) * L_SEQ + q0 + w * 16;
  float linv[4];
#pragma unroll
  for (int r = 0; r < 4; ++r) linv[r] = 1.f / __shfl(l_run, quad * 4 + r);
#pragma unroll
  for (int r = 0; r < 4; ++r) {
    size_t row = rb + quad * 4 + r;
#pragma unroll
    for (int n2 = 0; n2 < 8; ++n2)
      Opart[row * HD + n2 * 16 + l15] = __float2bfloat16(o[n2][r] * linv[r]);
  }
  if (quad == 0) ml[rb + l15] = make_float2(m_run, l_run);
}

// ---------------------------------------------------------------------------
// Combine the two KV-split halves (verified R6).
// ---------------------------------------------------------------------------
__global__ __launch_bounds__(256)
void attn_combine(const __hip_bfloat16* __restrict__ Opart,
                  const float2* __restrict__ ml,
                  __hip_bfloat16* __restrict__ out) {
  const int h  = blockIdx.y;
  const int q  = blockIdx.x * 16 + (threadIdx.x >> 4);
  const int d8 = (threadIdx.x & 15) * 8;
  const size_t i0 = (size_t)h * L_SEQ + q;
  const size_t i1 = (size_t)(NH + h) * L_SEQ + q;
  float2 a = ml[i0], b = ml[i1];
  float M  = fmaxf(a.x, b.x);
  float w1 = __expf(a.x - M) * a.y;
  float w2 = __expf(b.x - M) * b.y;
  float inv = 1.f / (w1 + w2);
  w1 *= inv; w2 *= inv;
  short8 o1 = *(const short8*)&Opart[i0 * HD + d8];
  short8 o2 = *(const short8*)&Opart[i1 * HD + d8];
  short8 r;
#pragma unroll
  for (int j = 0; j < 8; ++j)
    r[j] = bf16bits(w1 * bits2f(o1[j]) + w2 * bits2f(o2[j]));
  *(short8*)&out[(size_t)q * DIM + h * HD + d8] = r;
}

// ---------------------------------------------------------------------------
extern "C" void kernel_launch(void* const* d_in, const int* in_sizes, int n_in,
                              void* d_out, int out_size, void* d_ws, size_t ws_size,
                              hipStream_t stream) {
  const float* x       = (const float*)d_in[0];
  const float* pe      = (const float*)d_in[1];
  const float* qkv_w   = (const float*)d_in[2];
  const float* q_scale = (const float*)d_in[3];
  const float* k_scale = (const float*)d_in[4];
  const float* proj_w  = (const float*)d_in[5];
  const float* proj_b  = (const float*)d_in[6];
  float* out = (float*)d_out;

  // Workspace layout (exactly 67,108,864 B):
  //  [0, 8.4M):      xb (x bf16)        -> attn_out after gemm_qkv_fused
  //  [8.4M, 33.6M):  wb (qkv_w bf16)    -> Opart@8.4M (16.8M) + ml@25.2M
  //  [33.6M, 42M):   Qb   [42M, 50.3M): Kb   [50.3M, 58.7M): Vt
  //  [58.7M, 67.1M): pwb (proj_w bf16)
  char* base = (char*)d_ws;
  __hip_bfloat16* xb       = (__hip_bfloat16*)base;
  __hip_bfloat16* wb       = (__hip_bfloat16*)(base + 8388608);
  __hip_bfloat16* Qb       = (__hip_bfloat16*)(base + 33554432);
  __hip_bfloat16* Kb       = (__hip_bfloat16*)(base + 41943040);
  __hip_bfloat16* Vt       = (__hip_bfloat16*)(base + 50331648);
  __hip_bfloat16* pwb      = (__hip_bfloat16*)(base + 58720256);
  __hip_bfloat16* Opart    = (__hip_bfloat16*)(base + 8388608);
  float2*         ml       = (float2*)(base + 25165824);
  __hip_bfloat16* attn_out = (__hip_bfloat16*)base;

  cast2_bf16<<<dim3((DIM * DIM + TDIM * DIM) / (256 * 8)), 256, 0, stream>>>(
      x, xb, qkv_w, wb);

  gemm_qkv_fused<<<dim3(TDIM / 128, L_SEQ / 128), 256, 0, stream>>>(
      xb, wb, q_scale, k_scale, pe, Qb, Kb, Vt);

  cast_bf16<<<dim3(DIM * DIM / (256 * 8)), 256, 0, stream>>>(proj_w, pwb, DIM * DIM);

  attn_mfma<<<dim3(L_SEQ / 64, NH, 2), 256, 0, stream>>>(Qb, Kb, Vt, Opart, ml);
  attn_combine<<<dim3(L_SEQ / 16, NH), 256, 0, stream>>>(Opart, ml, attn_out);

  gemm_proj<<<dim3(DIM / 128, DIM / 128), 256, 0, stream>>>(
      attn_out, pwb, proj_b, out, L_SEQ, DIM, DIM);
}